// Round 7
// baseline (221.458 us; speedup 1.0000x reference)
//
#include <hip/hip_runtime.h>
#include <hip/hip_bf16.h>
#include <stdint.h>

// TT linear 4096->4096, B=2048, ranks (1,16,16,16,1), modes 8^4.
// R7: best-known LDS GEMM (R3: 128x128 tile, BK=64, XOR swizzle, 0 bank
// conflicts) + split-K=2 (grid 1024 = 4 blocks/CU = 16 waves/CU for
// barrier-drain hiding) with atomicAdd epilogue onto bias-initialized C.
// cvt_x + build_w fused into one prep kernel.

typedef __bf16 bf16_t;
typedef __bf16 bf16x8 __attribute__((ext_vector_type(8)));
typedef float floatx4 __attribute__((ext_vector_type(4)));

#define BATCH_N 2048
#define KD 4096
#define ND 4096

__device__ static inline void load_lds16(const void* g, void* l) {
    __builtin_amdgcn_global_load_lds(
        (const __attribute__((address_space(1))) void*)g,
        (__attribute__((address_space(3))) void*)l, 16, 0, 0);
}

// ---- fused prep: blocks [0,4096) build W (row-major [j][i] bf16);
//      blocks [4096,8192) cvt x fp32 -> bf16 --------------------------
__global__ __launch_bounds__(256) void prep(const float* __restrict__ x,
                                            const float* __restrict__ c0,
                                            const float* __restrict__ c1,
                                            const float* __restrict__ c2,
                                            const float* __restrict__ c3,
                                            bf16_t* __restrict__ W,
                                            bf16_t* __restrict__ xb) {
    __shared__ float c0s[8 * 16];       // [m0][r1]
    __shared__ float c1s[16 * 8 * 16];  // [r1][m1][r2]
    __shared__ float c2s[16 * 8 * 16];  // [r2][n2][r3]
    __shared__ float c3s[16 * 8];       // [r3][n3]
    __shared__ float Ps[64 * 16];       // [m01][r2]
    __shared__ float T1s[16 * 64];      // [r2][n23]
    const int t = threadIdx.x;

    if (blockIdx.x >= 4096) {           // ---- cvt_x ----
        int g = (blockIdx.x - 4096) * 256 + t;
        const float4* xv = (const float4*)x;
        float4 a = xv[g * 2];
        float4 b = xv[g * 2 + 1];
        bf16x8 o;
        o[0] = (bf16_t)a.x; o[1] = (bf16_t)a.y; o[2] = (bf16_t)a.z; o[3] = (bf16_t)a.w;
        o[4] = (bf16_t)b.x; o[5] = (bf16_t)b.y; o[6] = (bf16_t)b.z; o[7] = (bf16_t)b.w;
        ((bf16x8*)xb)[g] = o;
        return;
    }

    // ---- build_w: one block per (M23, N01) 64x64 W-tile ----
    const int b = blockIdx.x;
    const int M23 = b >> 6, N01 = b & 63;
    const int n0 = N01 >> 3, n1 = N01 & 7, m2 = M23 >> 3, m3 = M23 & 7;

    if (t < 128) c0s[t] = c0[(t >> 4) * 128 + n0 * 16 + (t & 15)];
    if (t < 128) c3s[t] = c3[((t >> 3) * 8 + m3) * 8 + (t & 7)];
    for (int i = t; i < 2048; i += 256) {
        int r1 = i >> 7, m1 = (i >> 4) & 7, r2 = i & 15;
        c1s[i] = c1[(r1 * 8 + m1) * 128 + n1 * 16 + r2];
    }
    for (int i = t; i < 2048; i += 256) {
        int r2 = i >> 7, n2 = (i >> 4) & 7, r3 = i & 15;
        c2s[i] = c2[(r2 * 8 + m2) * 128 + n2 * 16 + r3];
    }
    __syncthreads();

    for (int i = t; i < 1024; i += 256) {   // Ps[m01][r2]
        int m01 = i >> 4, r2 = i & 15, m0 = m01 >> 3, m1 = m01 & 7;
        float s = 0.f;
#pragma unroll
        for (int r1 = 0; r1 < 16; ++r1)
            s += c0s[m0 * 16 + r1] * c1s[r1 * 128 + m1 * 16 + r2];
        Ps[i] = s;
    }
    for (int i = t; i < 1024; i += 256) {   // T1s[r2][n23]
        int r2 = i >> 6, n23 = i & 63, n2 = n23 >> 3, n3 = n23 & 7;
        float s = 0.f;
#pragma unroll
        for (int r3 = 0; r3 < 16; ++r3)
            s += c2s[r2 * 128 + n2 * 16 + r3] * c3s[r3 * 8 + n3];
        T1s[i] = s;
    }
    __syncthreads();

    const int n23 = t & 63, q = t >> 6;
#pragma unroll
    for (int g = 0; g < 16; ++g) {
        int m01 = q * 16 + g;
        float s = 0.f;
#pragma unroll
        for (int r2 = 0; r2 < 16; ++r2) s += Ps[m01 * 16 + r2] * T1s[r2 * 64 + n23];
        W[(size_t)(m01 * 64 + M23) * 4096 + N01 * 64 + n23] = (bf16_t)s;
    }
}

// ---- C = broadcast(bias): 2M float4 stores ----------------------------
__global__ __launch_bounds__(256) void init_out(const float* __restrict__ bias,
                                                float* __restrict__ C) {
    int idx = blockIdx.x * 256 + threadIdx.x;   // 2,097,152
    int col = (idx * 4) & (ND - 1);
    float4 bv = *(const float4*)(bias + col);
    ((float4*)C)[idx] = bv;
}

// ---- BT GEMM, split-K=2: C[m,n] += sum_k A[m,k]*B[n,k] over K-half ----
// 128x128 tile, BK=64, 256 threads (waves 2x2, each 64x64 = 4x4 frags,
// 32 MFMA per K-iter). LDS row-major [row][64k], 16B-chunk XOR swizzle:
// phys_chunk = logical_chunk ^ (row & 7); staging global_load_lds w=16.
// grid (32, 16, 2); kz = K-half; atomicAdd epilogue (2-way contention).
__global__ __launch_bounds__(256, 4) void gemm_bt(const bf16_t* __restrict__ A,
                                                  const bf16_t* __restrict__ B,
                                                  float* __restrict__ C) {
    __shared__ bf16_t As[128 * 64];   // 16 KB
    __shared__ bf16_t Bs[128 * 64];   // 16 KB
    const int t = threadIdx.x;
    const int bn = blockIdx.x, bm = blockIdx.y, kz = blockIdx.z;
    const int lane = t & 63, wave = t >> 6;
    const int wm = wave >> 1, wn = wave & 1;

    // staging: call j (0..3), wave w: rows [(j*4+w)*8, +8) of 128-row tile.
    // lane l: row offset l>>3, logical 16B-chunk (l&7)^(l>>3)  [phys = l&7]
    const int srow = lane >> 3;
    const int lc = (lane & 7) ^ srow;
    const bf16_t* Agp = A + (size_t)(bm * 128 + wave * 8 + srow) * KD + lc * 8;
    const bf16_t* Bgp = B + (size_t)(bn * 128 + wave * 8 + srow) * KD + lc * 8;
    bf16_t* AsW = As + wave * 512;
    bf16_t* BsW = Bs + wave * 512;

    floatx4 acc[4][4];
    floatx4 zero = {0.f, 0.f, 0.f, 0.f};
#pragma unroll
    for (int i = 0; i < 4; ++i)
#pragma unroll
        for (int j = 0; j < 4; ++j) acc[i][j] = zero;

    const int fr = lane & 15;
    const int fc = lane >> 4;

    const int kbeg = kz * (KD / 2);
    for (int k0 = kbeg; k0 < kbeg + KD / 2; k0 += 64) {
        __syncthreads();
#pragma unroll
        for (int j = 0; j < 4; ++j) {
            load_lds16(Agp + (size_t)(j * 32) * KD + k0, AsW + j * 2048);
            load_lds16(Bgp + (size_t)(j * 32) * KD + k0, BsW + j * 2048);
        }
        __syncthreads();

#pragma unroll
        for (int kk = 0; kk < 2; ++kk) {
            const int pA = (fc + kk * 4) ^ (fr & 7);
            bf16x8 af[4], bf[4];
#pragma unroll
            for (int im = 0; im < 4; ++im)
                af[im] = *(const bf16x8*)(As + (wm * 64 + im * 16 + fr) * 64 + pA * 8);
#pragma unroll
            for (int in = 0; in < 4; ++in)
                bf[in] = *(const bf16x8*)(Bs + (wn * 64 + in * 16 + fr) * 64 + pA * 8);
#pragma unroll
            for (int im = 0; im < 4; ++im)
#pragma unroll
                for (int in = 0; in < 4; ++in)
                    acc[im][in] = __builtin_amdgcn_mfma_f32_16x16x32_bf16(
                        af[im], bf[in], acc[im][in], 0, 0, 0);
        }
    }

    // epilogue: D[m=(lane>>4)*4+reg][n=lane&15], atomic accumulate
    const int rl = lane >> 4, cl = lane & 15;
    const size_t rbase = (size_t)bm * 128 + wm * 64;
    const int cbase = bn * 128 + wn * 64;
#pragma unroll
    for (int im = 0; im < 4; ++im) {
#pragma unroll
        for (int in = 0; in < 4; ++in) {
            int col = cbase + in * 16 + cl;
#pragma unroll
            for (int r = 0; r < 4; ++r) {
                size_t row = rbase + im * 16 + rl * 4 + r;
                atomicAdd(&C[row * ND + col], acc[im][in][r]);
            }
        }
    }
}

extern "C" void kernel_launch(void* const* d_in, const int* in_sizes, int n_in,
                              void* d_out, int out_size, void* d_ws, size_t ws_size,
                              hipStream_t stream) {
    const float* x  = (const float*)d_in[0];
    const float* c0 = (const float*)d_in[1];
    const float* c1 = (const float*)d_in[2];
    const float* c2 = (const float*)d_in[3];
    const float* c3 = (const float*)d_in[4];
    const float* bias = (const float*)d_in[5];
    float* out = (float*)d_out;

    char* ws = (char*)d_ws;
    bf16_t* Xb = (bf16_t*)ws;                 // 16 MiB
    bf16_t* W  = (bf16_t*)(ws + (16u << 20)); // 32 MiB

    prep<<<8192, 256, 0, stream>>>(x, c0, c1, c2, c3, W, Xb);
    init_out<<<8192, 256, 0, stream>>>(bias, out);
    dim3 grid(ND / 128, BATCH_N / 128, 2);
    gemm_bt<<<grid, 256, 0, stream>>>(Xb, W, out);
}

// Round 8
// 179.971 us; speedup vs baseline: 1.2305x; 1.2305x over previous
//
#include <hip/hip_runtime.h>
#include <hip/hip_bf16.h>
#include <stdint.h>

// TT linear 4096->4096, B=2048, ranks (1,16,16,16,1), modes 8^4.
// R8 (consolidation): R3's best GEMM (128x128 tile, BK=64, XOR-swizzled
// LDS, 0 bank conflicts, 904 TF) + R7's fused prep (cvt_x + build_w, one
// launch) + XCD-aware grid swizzle on the GEMM. Bias in epilogue.

typedef __bf16 bf16_t;
typedef __bf16 bf16x8 __attribute__((ext_vector_type(8)));
typedef float floatx4 __attribute__((ext_vector_type(4)));

#define BATCH_N 2048
#define KD 4096
#define ND 4096

__device__ static inline void load_lds16(const void* g, void* l) {
    __builtin_amdgcn_global_load_lds(
        (const __attribute__((address_space(1))) void*)g,
        (__attribute__((address_space(3))) void*)l, 16, 0, 0);
}

// ---- fused prep: blocks [0,4096) build W (row-major [j][i] bf16);
//      blocks [4096,8192) cvt x fp32 -> bf16 ----------------------------
__global__ __launch_bounds__(256) void prep(const float* __restrict__ x,
                                            const float* __restrict__ c0,
                                            const float* __restrict__ c1,
                                            const float* __restrict__ c2,
                                            const float* __restrict__ c3,
                                            bf16_t* __restrict__ W,
                                            bf16_t* __restrict__ xb) {
    __shared__ float c0s[8 * 16];       // [m0][r1]
    __shared__ float c1s[16 * 8 * 16];  // [r1][m1][r2]
    __shared__ float c2s[16 * 8 * 16];  // [r2][n2][r3]
    __shared__ float c3s[16 * 8];       // [r3][n3]
    __shared__ float Ps[64 * 16];       // [m01][r2]
    __shared__ float T1s[16 * 64];      // [r2][n23]
    const int t = threadIdx.x;

    if (blockIdx.x >= 4096) {           // ---- cvt_x ----
        int g = (blockIdx.x - 4096) * 256 + t;
        const float4* xv = (const float4*)x;
        float4 a = xv[g * 2];
        float4 b = xv[g * 2 + 1];
        bf16x8 o;
        o[0] = (bf16_t)a.x; o[1] = (bf16_t)a.y; o[2] = (bf16_t)a.z; o[3] = (bf16_t)a.w;
        o[4] = (bf16_t)b.x; o[5] = (bf16_t)b.y; o[6] = (bf16_t)b.z; o[7] = (bf16_t)b.w;
        ((bf16x8*)xb)[g] = o;
        return;
    }

    // ---- build_w: one block per (M23, N01) 64x64 W-tile ----
    const int b = blockIdx.x;
    const int M23 = b >> 6, N01 = b & 63;
    const int n0 = N01 >> 3, n1 = N01 & 7, m2 = M23 >> 3, m3 = M23 & 7;

    if (t < 128) c0s[t] = c0[(t >> 4) * 128 + n0 * 16 + (t & 15)];
    if (t < 128) c3s[t] = c3[((t >> 3) * 8 + m3) * 8 + (t & 7)];
    for (int i = t; i < 2048; i += 256) {
        int r1 = i >> 7, m1 = (i >> 4) & 7, r2 = i & 15;
        c1s[i] = c1[(r1 * 8 + m1) * 128 + n1 * 16 + r2];
    }
    for (int i = t; i < 2048; i += 256) {
        int r2 = i >> 7, n2 = (i >> 4) & 7, r3 = i & 15;
        c2s[i] = c2[(r2 * 8 + m2) * 128 + n2 * 16 + r3];
    }
    __syncthreads();

    for (int i = t; i < 1024; i += 256) {   // Ps[m01][r2]
        int m01 = i >> 4, r2 = i & 15, m0 = m01 >> 3, m1 = m01 & 7;
        float s = 0.f;
#pragma unroll
        for (int r1 = 0; r1 < 16; ++r1)
            s += c0s[m0 * 16 + r1] * c1s[r1 * 128 + m1 * 16 + r2];
        Ps[i] = s;
    }
    for (int i = t; i < 1024; i += 256) {   // T1s[r2][n23]
        int r2 = i >> 6, n23 = i & 63, n2 = n23 >> 3, n3 = n23 & 7;
        float s = 0.f;
#pragma unroll
        for (int r3 = 0; r3 < 16; ++r3)
            s += c2s[r2 * 128 + n2 * 16 + r3] * c3s[r3 * 8 + n3];
        T1s[i] = s;
    }
    __syncthreads();

    const int n23 = t & 63, q = t >> 6;
#pragma unroll
    for (int g = 0; g < 16; ++g) {
        int m01 = q * 16 + g;
        float s = 0.f;
#pragma unroll
        for (int r2 = 0; r2 < 16; ++r2) s += Ps[m01 * 16 + r2] * T1s[r2 * 64 + n23];
        W[(size_t)(m01 * 64 + M23) * 4096 + N01 * 64 + n23] = (bf16_t)s;
    }
}

// ---- BT GEMM: C[m,n] = sum_k A[m,k]*B[n,k] + bias[n] ------------------
// 128x128 tile, BK=64, 256 threads (waves 2x2, each 64x64 = 4x4 frags,
// 32 MFMA per K-iter). LDS row-major [row][64k], 16B-chunk XOR swizzle:
// phys_chunk = logical_chunk ^ (row & 7); staging via global_load_lds w=16
// (swizzle applied on the global-source side; LDS dest stays lane-linear).
// Grid: 512 linear blocks, XCD-swizzled: xcd = bid&7 -> bm = xcd*2+(g&1),
// so the ~64 blocks landing on one XCD share 2 A-row-panels (L2-resident).
__global__ __launch_bounds__(256, 2) void gemm_bt(const bf16_t* __restrict__ A,
                                                  const bf16_t* __restrict__ B,
                                                  const float* __restrict__ bias,
                                                  float* __restrict__ C) {
    __shared__ bf16_t As[128 * 64];   // 16 KB
    __shared__ bf16_t Bs[128 * 64];   // 16 KB
    const int t = threadIdx.x;
    // XCD-aware swizzle of the 512-block grid onto (bm in [0,16), bn in [0,32))
    const int bid = blockIdx.x;
    const int xcd = bid & 7, g8 = bid >> 3;
    const int bm = xcd * 2 + (g8 & 1);
    const int bn = g8 >> 1;
    const int lane = t & 63, wave = t >> 6;
    const int wm = wave >> 1, wn = wave & 1;

    // staging: call j (0..3), wave w: rows [(j*4+w)*8, +8) of 128-row tile.
    // lane l: row offset l>>3, logical 16B-chunk (l&7)^(l>>3)  [phys = l&7]
    const int srow = lane >> 3;
    const int lc = (lane & 7) ^ srow;
    const bf16_t* Agp = A + (size_t)(bm * 128 + wave * 8 + srow) * KD + lc * 8;
    const bf16_t* Bgp = B + (size_t)(bn * 128 + wave * 8 + srow) * KD + lc * 8;
    bf16_t* AsW = As + wave * 512;
    bf16_t* BsW = Bs + wave * 512;

    floatx4 acc[4][4];
    floatx4 zero = {0.f, 0.f, 0.f, 0.f};
#pragma unroll
    for (int i = 0; i < 4; ++i)
#pragma unroll
        for (int j = 0; j < 4; ++j) acc[i][j] = zero;

    const int fr = lane & 15;
    const int fc = lane >> 4;

    for (int k0 = 0; k0 < KD; k0 += 64) {
        __syncthreads();
#pragma unroll
        for (int j = 0; j < 4; ++j) {
            load_lds16(Agp + (size_t)(j * 32) * KD + k0, AsW + j * 2048);
            load_lds16(Bgp + (size_t)(j * 32) * KD + k0, BsW + j * 2048);
        }
        __syncthreads();

#pragma unroll
        for (int kk = 0; kk < 2; ++kk) {
            const int pA = (fc + kk * 4) ^ (fr & 7);
            bf16x8 af[4], bf[4];
#pragma unroll
            for (int im = 0; im < 4; ++im)
                af[im] = *(const bf16x8*)(As + (wm * 64 + im * 16 + fr) * 64 + pA * 8);
#pragma unroll
            for (int in = 0; in < 4; ++in)
                bf[in] = *(const bf16x8*)(Bs + (wn * 64 + in * 16 + fr) * 64 + pA * 8);
#pragma unroll
            for (int im = 0; im < 4; ++im)
#pragma unroll
                for (int in = 0; in < 4; ++in)
                    acc[im][in] = __builtin_amdgcn_mfma_f32_16x16x32_bf16(
                        af[im], bf[in], acc[im][in], 0, 0, 0);
        }
    }

    // epilogue: D[m=(lane>>4)*4+reg][n=lane&15]
    const int rl = lane >> 4, cl = lane & 15;
    const size_t rbase = (size_t)bm * 128 + wm * 64;
    const int cbase = bn * 128 + wn * 64;
#pragma unroll
    for (int im = 0; im < 4; ++im) {
#pragma unroll
        for (int in = 0; in < 4; ++in) {
            int col = cbase + in * 16 + cl;
            float bv = bias[col];
#pragma unroll
            for (int r = 0; r < 4; ++r) {
                size_t row = rbase + im * 16 + rl * 4 + r;
                C[row * ND + col] = acc[im][in][r] + bv;
            }
        }
    }
}

extern "C" void kernel_launch(void* const* d_in, const int* in_sizes, int n_in,
                              void* d_out, int out_size, void* d_ws, size_t ws_size,
                              hipStream_t stream) {
    const float* x  = (const float*)d_in[0];
    const float* c0 = (const float*)d_in[1];
    const float* c1 = (const float*)d_in[2];
    const float* c2 = (const float*)d_in[3];
    const float* c3 = (const float*)d_in[4];
    const float* bias = (const float*)d_in[5];
    float* out = (float*)d_out;

    char* ws = (char*)d_ws;
    bf16_t* Xb = (bf16_t*)ws;                 // 16 MiB
    bf16_t* W  = (bf16_t*)(ws + (16u << 20)); // 32 MiB

    prep<<<8192, 256, 0, stream>>>(x, c0, c1, c2, c3, W, Xb);
    gemm_bt<<<512, 256, 0, stream>>>(Xb, W, bias, out);
}